// Round 5
// baseline (63.817 us; speedup 1.0000x reference)
//
#include <hip/hip_runtime.h>

// Problem constants
#define BATCH 2048
#define IN    512
#define OUT   512
#define NG    8
#define KTOT  1024   // concatenated K: [S | silu] x [Cw | w_b]

// GEMM tiling
#define BM 64
#define BN 64
#define BK 64
#define PAD 88                 // shorts per LDS row: 176B, 16B-aligned, <=2-way banks (free)
#define NIT (KTOT / BK)        // 16
#define NBLK 256               // grid size; 1 block/CU -> all co-resident

typedef __attribute__((ext_vector_type(8))) short bf16x8;
typedef __attribute__((ext_vector_type(4))) float f32x4;

__device__ inline unsigned short f2bf(float f) {
    union { float f; unsigned int u; } v; v.f = f;
    unsigned int r = v.u + 0x7fffu + ((v.u >> 16) & 1u);
    return (unsigned short)(r >> 16);
}

// ---------------------------------------------------------------------------
// Single fused kernel: per-block prep of its XCD-local A' rows + 2 B' rows,
// device-wide barrier, then the (verified) 64x64 MFMA GEMM.
//   A'[b][i] = sum_n exp(-(x[b,i]-g_n)^2)   A'[b][512+i] = silu(x[b,i])
//   B'[o][i] = (sum_a c[a,o,i]) * w_s[o,i]  B'[o][512+i] = w_b[o,i]
// Spline via uniform-grid factorization: 3 exp + Horner instead of 9 exp.
// ---------------------------------------------------------------------------
__global__ __launch_bounds__(512) void fused_kernel(const float* __restrict__ x,
                                                    const float* __restrict__ c,
                                                    const float* __restrict__ w_b,
                                                    const float* __restrict__ w_s,
                                                    const float* __restrict__ grid,
                                                    unsigned short* __restrict__ A,
                                                    unsigned short* __restrict__ B,
                                                    float* __restrict__ outp,
                                                    unsigned int* __restrict__ flag) {
    __shared__ short As[2][BM * PAD];
    __shared__ short Bs[2][BN * PAD];

    int tid  = threadIdx.x;
    int bid  = blockIdx.x;
    // XCD-aware decode: mg = XCD id (bid%8), owns m rows [mg*256, mg*256+256)
    int mg   = bid & 7;
    int rest = bid >> 3;
    int sub  = rest >> 3;              // 0..3
    int ncol = rest & 7;               // 0..7
    int m0   = (mg * 4 + sub) * BM;
    int n0   = ncol * BN;

    // ---- phase 1a: prep 8 A'-rows (rows m0 + ncol*8 .. +8 -> XCD-local) ----
    {
        int row = m0 + ncol * 8 + (tid >> 6);   // 8 rows, 64 threads each
        int col = (tid & 63) * 8;
        float g0 = grid[0];
        float dl = grid[1] - g0;                // uniform spacing (4/7)
        float d2 = dl * dl;
        float dn[NG];
#pragma unroll
        for (int n = 0; n < NG; ++n) dn[n] = __expf(-d2 * (float)(n * n));
        int e = row * IN + col;
        float4 x0 = *(const float4*)&x[e];
        float4 x1 = *(const float4*)&x[e + 4];
        float xv[8] = {x0.x, x0.y, x0.z, x0.w, x1.x, x1.y, x1.z, x1.w};
        unsigned short sv[8], lv[8];
#pragma unroll
        for (int j = 0; j < 8; ++j) {
            float u  = xv[j] - g0;
            float e1 = __expf(-u * u);
            float q  = __expf(2.f * dl * u);
            float p  = dn[NG - 1];
#pragma unroll
            for (int n = NG - 2; n >= 0; --n) p = p * q + dn[n];
            sv[j] = f2bf(e1 * p);
            lv[j] = f2bf(xv[j] / (1.f + __expf(-xv[j])));
        }
        *(int4*)&A[row * KTOT + col]       = *(int4*)sv;
        *(int4*)&A[row * KTOT + 512 + col] = *(int4*)lv;
    }

    // ---- phase 1b: prep 2 B'-rows (threads 0..127) ----
    if (tid < 128) {
        int row = bid * 2 + (tid >> 6);
        int col = (tid & 63) * 8;
        int e = row * IN + col;
        float acc[8] = {};
#pragma unroll
        for (int a = 0; a < NG; ++a) {
            float4 c0 = *(const float4*)&c[(size_t)a * (OUT * IN) + e];
            float4 c1 = *(const float4*)&c[(size_t)a * (OUT * IN) + e + 4];
            acc[0] += c0.x; acc[1] += c0.y; acc[2] += c0.z; acc[3] += c0.w;
            acc[4] += c1.x; acc[5] += c1.y; acc[6] += c1.z; acc[7] += c1.w;
        }
        float4 s0 = *(const float4*)&w_s[e];
        float4 s1 = *(const float4*)&w_s[e + 4];
        float sw[8] = {s0.x, s0.y, s0.z, s0.w, s1.x, s1.y, s1.z, s1.w};
        float4 b0 = *(const float4*)&w_b[e];
        float4 b1 = *(const float4*)&w_b[e + 4];
        float bw[8] = {b0.x, b0.y, b0.z, b0.w, b1.x, b1.y, b1.z, b1.w};
        unsigned short cv[8], bv[8];
#pragma unroll
        for (int j = 0; j < 8; ++j) { cv[j] = f2bf(acc[j] * sw[j]); bv[j] = f2bf(bw[j]); }
        *(int4*)&B[row * KTOT + col]       = *(int4*)cv;
        *(int4*)&B[row * KTOT + 512 + col] = *(int4*)bv;
    }

    // ---- device-wide barrier (all blocks co-resident: 256 blocks, 1/CU) ----
    __syncthreads();                          // all block stores issued
    if (tid == 0)
        __hip_atomic_fetch_add(flag, 1u, __ATOMIC_ACQ_REL, __HIP_MEMORY_SCOPE_AGENT);
    // relaxed spin (no per-poll cache maintenance), one acquire at the end
    while (__hip_atomic_load(flag, __ATOMIC_RELAXED, __HIP_MEMORY_SCOPE_AGENT) < NBLK)
        __builtin_amdgcn_s_sleep(8);
    (void)__hip_atomic_load(flag, __ATOMIC_ACQUIRE, __HIP_MEMORY_SCOPE_AGENT);
    __syncthreads();

    // ---- phase 2: GEMM (identical to verified round-4 kernel) ----
    int lane = tid & 63;
    int w    = tid >> 6;               // 0..7
    int wm   = w >> 1, wn = w & 1;     // 4x2 wave grid over 64x64 tile
    int lr   = lane & 15, lg = lane >> 4;

    int srow = tid >> 3;   // 0..63
    int sc8  = tid & 7;

    const int4* Ag = (const int4*)&A[(size_t)(m0 + srow) * KTOT + sc8 * 8];
    const int4* Bg = (const int4*)&B[(size_t)(n0 + srow) * KTOT + sc8 * 8];
    int wo = srow * PAD + sc8 * 8;

    f32x4 acc0 = {0.f, 0.f, 0.f, 0.f};
    f32x4 acc1 = {0.f, 0.f, 0.f, 0.f};

    int4 ca = Ag[0], cb = Bg[0];
    *(int4*)&As[0][wo] = ca;
    *(int4*)&Bs[0][wo] = cb;
    ca = Ag[8]; cb = Bg[8];
    __syncthreads();

#pragma unroll
    for (int it = 0; it < NIT; ++it) {
        int cur = it & 1;
        if (it + 1 < NIT) {
            *(int4*)&As[cur ^ 1][wo] = ca;
            *(int4*)&Bs[cur ^ 1][wo] = cb;
            if (it + 2 < NIT) { ca = Ag[(it + 2) * 8]; cb = Bg[(it + 2) * 8]; }
        }
#pragma unroll
        for (int ks = 0; ks < 2; ++ks) {
            bf16x8 a  = *(const bf16x8*)&As[cur][(wm * 16 + lr)      * PAD + ks * 32 + lg * 8];
            bf16x8 b0 = *(const bf16x8*)&Bs[cur][(wn * 32 + lr)      * PAD + ks * 32 + lg * 8];
            bf16x8 b1 = *(const bf16x8*)&Bs[cur][(wn * 32 + 16 + lr) * PAD + ks * 32 + lg * 8];
            acc0 = __builtin_amdgcn_mfma_f32_16x16x32_bf16(a, b0, acc0, 0, 0, 0);
            acc1 = __builtin_amdgcn_mfma_f32_16x16x32_bf16(a, b1, acc1, 0, 0, 0);
        }
        __syncthreads();
    }

    // C/D layout: col = lane&15, row = (lane>>4)*4 + reg   [measured m89/m91]
    int orow = m0 + wm * 16 + lg * 4;
    int ocol = n0 + wn * 32 + lr;
#pragma unroll
    for (int r = 0; r < 4; ++r) {
        outp[(size_t)(orow + r) * OUT + ocol]      = acc0[r];
        outp[(size_t)(orow + r) * OUT + ocol + 16] = acc1[r];
    }
}

extern "C" void kernel_launch(void* const* d_in, const int* in_sizes, int n_in,
                              void* d_out, int out_size, void* d_ws, size_t ws_size,
                              hipStream_t stream) {
    (void)in_sizes; (void)n_in; (void)out_size; (void)ws_size;
    const float* x    = (const float*)d_in[0];
    const float* c    = (const float*)d_in[1];
    const float* w_b  = (const float*)d_in[2];
    const float* w_s  = (const float*)d_in[3];
    const float* grid = (const float*)d_in[4];
    float* outp = (float*)d_out;

    unsigned short* A = (unsigned short*)d_ws;             // 2048x1024 bf16 = 4 MiB
    unsigned short* B = A + (size_t)BATCH * KTOT;          // 512x1024 bf16 = 1 MiB
    unsigned int* flag = (unsigned int*)((char*)d_ws + (8u << 20));

    // reset barrier flag every call (handles 0xAA poison and prior-call value)
    hipMemsetAsync(flag, 0, sizeof(unsigned int), stream);
    fused_kernel<<<NBLK, 512, 0, stream>>>(x, c, w_b, w_s, grid, A, B, outp, flag);
}

// Round 6
// 26.973 us; speedup vs baseline: 2.3659x; 2.3659x over previous
//
#include <hip/hip_runtime.h>

// Problem constants
#define BATCH 2048
#define IN    512
#define OUT   512
#define NG    8
#define KTOT  1024   // concatenated K: [S | silu] x [Cw | w_b]

// GEMM tiling
#define BM 64
#define BN 64
#define BK 64
#define PAD 88                 // shorts per LDS row: 176B, 16B-aligned, <=2-way banks (free)
#define NITH 8                 // K-iters per K-half (split-K x2)

typedef __attribute__((ext_vector_type(8))) short bf16x8;
typedef __attribute__((ext_vector_type(4))) float f32x4;

__device__ inline unsigned short f2bf(float f) {
    union { float f; unsigned int u; } v; v.f = f;
    unsigned int r = v.u + 0x7fffu + ((v.u >> 16) & 1u);
    return (unsigned short)(r >> 16);
}

// ---------------------------------------------------------------------------
// Fused prep: blocks [0,512) build A' (bf16), blocks [512,640) build B' (bf16)
//   A'[b][i]      = sum_n exp(-(x[b,i]-g_n)^2)      A'[b][512+i] = silu(x[b,i])
//   B'[o][i]      = (sum_a c[a,o,i]) * w_s[o,i]     B'[o][512+i] = w_b[o,i]
// Spline via uniform-grid factorization: 3 exp + Horner instead of 9 exp.
// ---------------------------------------------------------------------------
__global__ __launch_bounds__(256) void prep_kernel(const float* __restrict__ x,
                                                   const float* __restrict__ c,
                                                   const float* __restrict__ w_b,
                                                   const float* __restrict__ w_s,
                                                   const float* __restrict__ grid,
                                                   unsigned short* __restrict__ A,
                                                   unsigned short* __restrict__ B) {
    int blk = blockIdx.x;
    int tid = threadIdx.x;
    if (blk < 512) {
        int e = (blk * 256 + tid) * 8;       // element base in x (row-aligned: 8 | 512)
        float g0 = grid[0];
        float dl = grid[1] - g0;             // uniform spacing (4/7)
        float d2 = dl * dl;
        float dn[NG];
#pragma unroll
        for (int n = 0; n < NG; ++n) dn[n] = __expf(-d2 * (float)(n * n));
        float4 x0 = *(const float4*)&x[e];
        float4 x1 = *(const float4*)&x[e + 4];
        float xv[8] = {x0.x, x0.y, x0.z, x0.w, x1.x, x1.y, x1.z, x1.w};
        unsigned short sv[8], lv[8];
#pragma unroll
        for (int j = 0; j < 8; ++j) {
            float u  = xv[j] - g0;
            float e1 = __expf(-u * u);
            float q  = __expf(2.f * dl * u);
            float p  = dn[NG - 1];
#pragma unroll
            for (int n = NG - 2; n >= 0; --n) p = p * q + dn[n];
            sv[j] = f2bf(e1 * p);
            lv[j] = f2bf(xv[j] / (1.f + __expf(-xv[j])));
        }
        int b = e >> 9, i = e & 511;
        *(int4*)&A[b * KTOT + i]       = *(int4*)sv;
        *(int4*)&A[b * KTOT + 512 + i] = *(int4*)lv;
    } else {
        int e = ((blk - 512) * 256 + tid) * 8;
        float acc[8] = {};
#pragma unroll
        for (int a = 0; a < NG; ++a) {
            float4 c0 = *(const float4*)&c[(size_t)a * (OUT * IN) + e];
            float4 c1 = *(const float4*)&c[(size_t)a * (OUT * IN) + e + 4];
            acc[0] += c0.x; acc[1] += c0.y; acc[2] += c0.z; acc[3] += c0.w;
            acc[4] += c1.x; acc[5] += c1.y; acc[6] += c1.z; acc[7] += c1.w;
        }
        float4 s0 = *(const float4*)&w_s[e];
        float4 s1 = *(const float4*)&w_s[e + 4];
        float sw[8] = {s0.x, s0.y, s0.z, s0.w, s1.x, s1.y, s1.z, s1.w};
        float4 b0 = *(const float4*)&w_b[e];
        float4 b1 = *(const float4*)&w_b[e + 4];
        float bw[8] = {b0.x, b0.y, b0.z, b0.w, b1.x, b1.y, b1.z, b1.w};
        unsigned short cv[8], bv[8];
#pragma unroll
        for (int j = 0; j < 8; ++j) { cv[j] = f2bf(acc[j] * sw[j]); bv[j] = f2bf(bw[j]); }
        int o = e >> 9, i = e & 511;
        *(int4*)&B[o * KTOT + i]       = *(int4*)cv;
        *(int4*)&B[o * KTOT + 512 + i] = *(int4*)bv;
    }
}

// ---------------------------------------------------------------------------
// bf16 MFMA GEMM, split-K x2 + ks-split waves:
//   out[2048][512] = A'[2048][1024] * B'[512][1024]^T
// 512 blocks: tile = bid&255 (round-4 XCD decode), khalf = bid>>8.
// 512 threads = 8 waves: (wm,wn) = 32x32 output quadrant, ks = K-slice of 32
// within each BK=64 step. Each wave: 4 ds_read_b128 : 4 MFMA (1:1).
// Double-buffered LDS, 1 barrier/iter, 2-deep reg prefetch.
// End: cross-ks LDS reduce, then unsafeAtomicAdd into zeroed out
// (exactly 2 addends/element -> deterministic).
// ---------------------------------------------------------------------------
__global__ __launch_bounds__(512) void gemm_kernel(const unsigned short* __restrict__ A,
                                                   const unsigned short* __restrict__ B,
                                                   float* __restrict__ outp) {
    __shared__ short As[2][BM * PAD];
    __shared__ short Bs[2][BN * PAD];

    int tid  = threadIdx.x;
    int lane = tid & 63;
    int w    = tid >> 6;               // 0..7
    int wm   = (w >> 2) & 1;
    int wn   = (w >> 1) & 1;
    int ks   = w & 1;                  // K-slice within BK
    int lr   = lane & 15, lg = lane >> 4;

    int bid   = blockIdx.x;
    int tile  = bid & 255;
    int khalf = bid >> 8;
    int mg   = tile & 7;               // XCD id
    int rest = tile >> 3;
    int sub  = rest >> 3;              // 0..3
    int ncol = rest & 7;               // 0..7
    int m0   = (mg * 4 + sub) * BM;
    int n0   = ncol * BN;

    int srow = tid >> 3;   // 0..63
    int sc8  = tid & 7;

    const int4* Ag = (const int4*)&A[(size_t)(m0 + srow) * KTOT + khalf * (NITH * BK) + sc8 * 8];
    const int4* Bg = (const int4*)&B[(size_t)(n0 + srow) * KTOT + khalf * (NITH * BK) + sc8 * 8];
    int wo = srow * PAD + sc8 * 8;

    f32x4 acc00 = {0.f, 0.f, 0.f, 0.f};
    f32x4 acc01 = {0.f, 0.f, 0.f, 0.f};
    f32x4 acc10 = {0.f, 0.f, 0.f, 0.f};
    f32x4 acc11 = {0.f, 0.f, 0.f, 0.f};

    // prologue: stage it=0 into buf0, prefetch it=1 into regs
    int4 ca = Ag[0], cb = Bg[0];
    *(int4*)&As[0][wo] = ca;
    *(int4*)&Bs[0][wo] = cb;
    ca = Ag[8]; cb = Bg[8];
    __syncthreads();

#pragma unroll
    for (int it = 0; it < NITH; ++it) {
        int cur = it & 1;
        if (it + 1 < NITH) {
            *(int4*)&As[cur ^ 1][wo] = ca;
            *(int4*)&Bs[cur ^ 1][wo] = cb;
            if (it + 2 < NITH) { ca = Ag[(it + 2) * 8]; cb = Bg[(it + 2) * 8]; }
        }
        bf16x8 a0 = *(const bf16x8*)&As[cur][(wm * 32 + lr)      * PAD + ks * 32 + lg * 8];
        bf16x8 a1 = *(const bf16x8*)&As[cur][(wm * 32 + 16 + lr) * PAD + ks * 32 + lg * 8];
        bf16x8 b0 = *(const bf16x8*)&Bs[cur][(wn * 32 + lr)      * PAD + ks * 32 + lg * 8];
        bf16x8 b1 = *(const bf16x8*)&Bs[cur][(wn * 32 + 16 + lr) * PAD + ks * 32 + lg * 8];
        acc00 = __builtin_amdgcn_mfma_f32_16x16x32_bf16(a0, b0, acc00, 0, 0, 0);
        acc01 = __builtin_amdgcn_mfma_f32_16x16x32_bf16(a0, b1, acc01, 0, 0, 0);
        acc10 = __builtin_amdgcn_mfma_f32_16x16x32_bf16(a1, b0, acc10, 0, 0, 0);
        acc11 = __builtin_amdgcn_mfma_f32_16x16x32_bf16(a1, b1, acc11, 0, 0, 0);
        __syncthreads();
    }

    // cross-ks reduce: ks=1 waves publish partials in LDS (reuse As: 16KB<=22KB)
    float* Ls = (float*)&As[0][0];
    int p = w >> 1;                    // quadrant id 0..3
    if (ks == 1) {
        *(f32x4*)&Ls[p * 1024 + lane * 16 + 0]  = acc00;
        *(f32x4*)&Ls[p * 1024 + lane * 16 + 4]  = acc01;
        *(f32x4*)&Ls[p * 1024 + lane * 16 + 8]  = acc10;
        *(f32x4*)&Ls[p * 1024 + lane * 16 + 12] = acc11;
    }
    __syncthreads();
    if (ks == 0) {
        f32x4 p00 = *(const f32x4*)&Ls[p * 1024 + lane * 16 + 0];
        f32x4 p01 = *(const f32x4*)&Ls[p * 1024 + lane * 16 + 4];
        f32x4 p10 = *(const f32x4*)&Ls[p * 1024 + lane * 16 + 8];
        f32x4 p11 = *(const f32x4*)&Ls[p * 1024 + lane * 16 + 12];
        // C/D layout: col = lane&15, row = (lane>>4)*4 + reg   [measured m89/m91]
        int orow = m0 + wm * 32 + lg * 4;
        int ocol = n0 + wn * 32 + lr;
#pragma unroll
        for (int r = 0; r < 4; ++r) {
            unsafeAtomicAdd(&outp[(size_t)(orow + r) * OUT + ocol],           acc00[r] + p00[r]);
            unsafeAtomicAdd(&outp[(size_t)(orow + r) * OUT + ocol + 16],      acc01[r] + p01[r]);
            unsafeAtomicAdd(&outp[(size_t)(orow + 16 + r) * OUT + ocol],      acc10[r] + p10[r]);
            unsafeAtomicAdd(&outp[(size_t)(orow + 16 + r) * OUT + ocol + 16], acc11[r] + p11[r]);
        }
    }
}

extern "C" void kernel_launch(void* const* d_in, const int* in_sizes, int n_in,
                              void* d_out, int out_size, void* d_ws, size_t ws_size,
                              hipStream_t stream) {
    (void)in_sizes; (void)n_in; (void)out_size; (void)ws_size;
    const float* x    = (const float*)d_in[0];
    const float* c    = (const float*)d_in[1];
    const float* w_b  = (const float*)d_in[2];
    const float* w_s  = (const float*)d_in[3];
    const float* grid = (const float*)d_in[4];
    float* outp = (float*)d_out;

    unsigned short* A = (unsigned short*)d_ws;             // 2048x1024 bf16 = 4 MiB
    unsigned short* B = A + (size_t)BATCH * KTOT;          // 512x1024 bf16 = 1 MiB

    // zero out for the atomic split-K accumulation (graph-capture-legal)
    hipMemsetAsync(d_out, 0, (size_t)BATCH * OUT * sizeof(float), stream);
    prep_kernel<<<512 + 128, 256, 0, stream>>>(x, c, w_b, w_s, grid, A, B);
    gemm_kernel<<<512, 512, 0, stream>>>(A, B, outp);
}

// Round 8
// 21.058 us; speedup vs baseline: 3.0305x; 1.2809x over previous
//
#include <hip/hip_runtime.h>

// Problem constants
#define BATCH 2048
#define IN    512
#define OUT   512
#define NG    8
#define KTOT  1024   // concatenated K: [S | silu] x [Cw | w_b]

// GEMM tiling: 64x64 tile, BK=64, tiled+swizzled workspace layout.
// ws layout: A_ws[mt=0..31][kt=0..15][64 rows][64 cols bf16] (8KB tiles),
//            B_ws[nt=0..7 ][kt=0..15][64 rows][64 cols bf16]
// Within a tile, 16B chunk c of row r is stored at chunk (c ^ (r&7))
// (XOR swizzle baked into the producer; ds_read applies the same XOR).
#define TILE_SHORTS 4096       // 64*64
#define NIT 16

typedef __attribute__((ext_vector_type(8))) short bf16x8;
typedef __attribute__((ext_vector_type(4))) float f32x4;

__device__ inline unsigned short f2bf(float f) {
    union { float f; unsigned int u; } v; v.f = f;
    unsigned int r = v.u + 0x7fffu + ((v.u >> 16) & 1u);
    return (unsigned short)(r >> 16);
}

__device__ inline void gload_lds16(const void* g, void* l) {
    __builtin_amdgcn_global_load_lds((const __attribute__((address_space(1))) void*)g,
                                     (__attribute__((address_space(3))) void*)l, 16, 0, 0);
}

// ---------------------------------------------------------------------------
// Fused prep: blocks [0,512) build A' (bf16), blocks [512,640) build B' (bf16)
//   A'[b][i] = sum_n exp(-(x[b,i]-g_n)^2)   A'[b][512+i] = silu(x[b,i])
//   B'[o][i] = (sum_a c[a,o,i]) * w_s[o,i]  B'[o][512+i] = w_b[o,i]
// Spline via uniform-grid factorization: 3 exp + Horner instead of 9 exp.
// Writes go to the tiled+swizzled ws layout (see above).
// ---------------------------------------------------------------------------
__global__ __launch_bounds__(256) void prep_kernel(const float* __restrict__ x,
                                                   const float* __restrict__ c,
                                                   const float* __restrict__ w_b,
                                                   const float* __restrict__ w_s,
                                                   const float* __restrict__ grid,
                                                   unsigned short* __restrict__ A,
                                                   unsigned short* __restrict__ B) {
    int blk = blockIdx.x;
    int tid = threadIdx.x;
    int lane6 = tid & 63;
    int kt = lane6 >> 3;           // 0..7 : K-tile within each 512-half
    int cc = lane6 & 7;            // 16B chunk within the 64-col tile
    if (blk < 512) {
        int b   = blk * 4 + (tid >> 6);      // global row 0..2047
        int e   = b * IN + lane6 * 8;
        int mt  = b >> 6, row = b & 63;
        int swc = cc ^ (row & 7);
        float g0 = grid[0];
        float dl = grid[1] - g0;             // uniform spacing (4/7)
        float d2 = dl * dl;
        float dn[NG];
#pragma unroll
        for (int n = 0; n < NG; ++n) dn[n] = __expf(-d2 * (float)(n * n));
        float4 x0 = *(const float4*)&x[e];
        float4 x1 = *(const float4*)&x[e + 4];
        float xv[8] = {x0.x, x0.y, x0.z, x0.w, x1.x, x1.y, x1.z, x1.w};
        unsigned short sv[8], lv[8];
#pragma unroll
        for (int j = 0; j < 8; ++j) {
            float u  = xv[j] - g0;
            float e1 = __expf(-u * u);
            float q  = __expf(2.f * dl * u);
            float p  = dn[NG - 1];
#pragma unroll
            for (int n = NG - 2; n >= 0; --n) p = p * q + dn[n];
            sv[j] = f2bf(e1 * p);
            lv[j] = f2bf(xv[j] / (1.f + __expf(-xv[j])));
        }
        *(int4*)&A[(mt * 16 + kt)     * TILE_SHORTS + row * 64 + swc * 8] = *(int4*)sv;
        *(int4*)&A[(mt * 16 + 8 + kt) * TILE_SHORTS + row * 64 + swc * 8] = *(int4*)lv;
    } else {
        int o   = (blk - 512) * 4 + (tid >> 6);   // global row 0..511
        int e   = o * IN + lane6 * 8;
        int nt  = o >> 6, row = o & 63;
        int swc = cc ^ (row & 7);
        float acc[8] = {};
#pragma unroll
        for (int a = 0; a < NG; ++a) {
            float4 c0 = *(const float4*)&c[(size_t)a * (OUT * IN) + e];
            float4 c1 = *(const float4*)&c[(size_t)a * (OUT * IN) + e + 4];
            acc[0] += c0.x; acc[1] += c0.y; acc[2] += c0.z; acc[3] += c0.w;
            acc[4] += c1.x; acc[5] += c1.y; acc[6] += c1.z; acc[7] += c1.w;
        }
        float4 s0 = *(const float4*)&w_s[e];
        float4 s1 = *(const float4*)&w_s[e + 4];
        float sw[8] = {s0.x, s0.y, s0.z, s0.w, s1.x, s1.y, s1.z, s1.w};
        float4 b0 = *(const float4*)&w_b[e];
        float4 b1 = *(const float4*)&w_b[e + 4];
        float bw[8] = {b0.x, b0.y, b0.z, b0.w, b1.x, b1.y, b1.z, b1.w};
        unsigned short cv[8], bv[8];
#pragma unroll
        for (int j = 0; j < 8; ++j) { cv[j] = f2bf(acc[j] * sw[j]); bv[j] = f2bf(bw[j]); }
        *(int4*)&B[(nt * 16 + kt)     * TILE_SHORTS + row * 64 + swc * 8] = *(int4*)cv;
        *(int4*)&B[(nt * 16 + 8 + kt) * TILE_SHORTS + row * 64 + swc * 8] = *(int4*)bv;
    }
}

// ---------------------------------------------------------------------------
// bf16 MFMA GEMM: out[2048][512] = A'[2048][1024] * B'[512][1024]^T
// 256 blocks (1/CU, round-4 XCD decode), 512 threads = 8 waves:
// (wm,wn) = 32x32 output quadrant, ks = K-slice of 32 within BK=64.
// global_load_lds (16B) staging into double-buffered linear LDS tiles,
// loads for it+1 issued at the TOP of iter it (latency hidden under
// ds_read+MFMA before the barrier drain). XOR-swizzled ds_read (both-sides
// swizzle with the pre-swizzled ws; rule #21).
// ---------------------------------------------------------------------------
__global__ __launch_bounds__(512) void gemm_kernel(const unsigned short* __restrict__ A,
                                                   const unsigned short* __restrict__ B,
                                                   float* __restrict__ outp) {
    __shared__ short As[2][TILE_SHORTS];
    __shared__ short Bs[2][TILE_SHORTS];

    int tid  = threadIdx.x;
    int lane = tid & 63;
    int w    = tid >> 6;               // 0..7
    int wm   = (w >> 2) & 1;
    int wn   = (w >> 1) & 1;
    int ks   = w & 1;                  // K-slice within BK
    int lr   = lane & 15, lg = lane >> 4;

    int bid  = blockIdx.x;
    int mg   = bid & 7;                // XCD id
    int rest = bid >> 3;
    int sub  = rest >> 3;              // 0..3
    int ncol = rest & 7;               // 0..7
    int mt   = mg * 4 + sub;           // 0..31
    int m0   = mt * 64;
    int n0   = ncol * 64;

    const unsigned short* Ab = A + (size_t)(mt * 16) * TILE_SHORTS;
    const unsigned short* Bb = B + (size_t)(ncol * 16) * TILE_SHORTS;

    // swizzled ds_read chunk: all four fragment rows are congruent to lr mod 8
    int swc  = ((ks * 4 + lg) ^ (lr & 7)) * 8;
    int ra0  = (wm * 32 + lr)      * 64 + swc;
    int ra1  = (wm * 32 + 16 + lr) * 64 + swc;
    int rb0  = (wn * 32 + lr)      * 64 + swc;
    int rb1  = (wn * 32 + 16 + lr) * 64 + swc;

    f32x4 acc00 = {0.f, 0.f, 0.f, 0.f};
    f32x4 acc01 = {0.f, 0.f, 0.f, 0.f};
    f32x4 acc10 = {0.f, 0.f, 0.f, 0.f};
    f32x4 acc11 = {0.f, 0.f, 0.f, 0.f};

    // prologue: stage it=0 into buf0
    gload_lds16(Ab + tid * 8, &As[0][tid * 8]);
    gload_lds16(Bb + tid * 8, &Bs[0][tid * 8]);
    __syncthreads();

#pragma unroll
    for (int it = 0; it < NIT; ++it) {
        int cur = it & 1;
        if (it + 1 < NIT) {   // issue next-tile loads FIRST (hide under compute)
            gload_lds16(Ab + (it + 1) * TILE_SHORTS + tid * 8, &As[cur ^ 1][tid * 8]);
            gload_lds16(Bb + (it + 1) * TILE_SHORTS + tid * 8, &Bs[cur ^ 1][tid * 8]);
        }
        bf16x8 a0 = *(const bf16x8*)&As[cur][ra0];
        bf16x8 a1 = *(const bf16x8*)&As[cur][ra1];
        bf16x8 b0 = *(const bf16x8*)&Bs[cur][rb0];
        bf16x8 b1 = *(const bf16x8*)&Bs[cur][rb1];
        acc00 = __builtin_amdgcn_mfma_f32_16x16x32_bf16(a0, b0, acc00, 0, 0, 0);
        acc01 = __builtin_amdgcn_mfma_f32_16x16x32_bf16(a0, b1, acc01, 0, 0, 0);
        acc10 = __builtin_amdgcn_mfma_f32_16x16x32_bf16(a1, b0, acc10, 0, 0, 0);
        acc11 = __builtin_amdgcn_mfma_f32_16x16x32_bf16(a1, b1, acc11, 0, 0, 0);
        __syncthreads();
    }

    // cross-ks reduce: ks=1 waves publish partials in LDS (16KB = As exactly)
    float* Ls = (float*)&As[0][0];
    int p = w >> 1;                    // quadrant id 0..3
    if (ks == 1) {
        *(f32x4*)&Ls[p * 1024 + lane * 16 + 0]  = acc00;
        *(f32x4*)&Ls[p * 1024 + lane * 16 + 4]  = acc01;
        *(f32x4*)&Ls[p * 1024 + lane * 16 + 8]  = acc10;
        *(f32x4*)&Ls[p * 1024 + lane * 16 + 12] = acc11;
    }
    __syncthreads();
    if (ks == 0) {
        f32x4 p00 = *(const f32x4*)&Ls[p * 1024 + lane * 16 + 0];
        f32x4 p01 = *(const f32x4*)&Ls[p * 1024 + lane * 16 + 4];
        f32x4 p10 = *(const f32x4*)&Ls[p * 1024 + lane * 16 + 8];
        f32x4 p11 = *(const f32x4*)&Ls[p * 1024 + lane * 16 + 12];
        // C/D layout: col = lane&15, row = (lane>>4)*4 + reg   [measured m89/m91]
        int orow = m0 + wm * 32 + lg * 4;
        int ocol = n0 + wn * 32 + lr;
#pragma unroll
        for (int r = 0; r < 4; ++r) {
            outp[(size_t)(orow + r) * OUT + ocol]           = acc00[r] + p00[r];
            outp[(size_t)(orow + r) * OUT + ocol + 16]      = acc01[r] + p01[r];
            outp[(size_t)(orow + 16 + r) * OUT + ocol]      = acc10[r] + p10[r];
            outp[(size_t)(orow + 16 + r) * OUT + ocol + 16] = acc11[r] + p11[r];
        }
    }
}

extern "C" void kernel_launch(void* const* d_in, const int* in_sizes, int n_in,
                              void* d_out, int out_size, void* d_ws, size_t ws_size,
                              hipStream_t stream) {
    (void)in_sizes; (void)n_in; (void)out_size; (void)ws_size;
    const float* x    = (const float*)d_in[0];
    const float* c    = (const float*)d_in[1];
    const float* w_b  = (const float*)d_in[2];
    const float* w_s  = (const float*)d_in[3];
    const float* grid = (const float*)d_in[4];
    float* outp = (float*)d_out;

    unsigned short* A = (unsigned short*)d_ws;             // 32*16 tiles = 4 MiB
    unsigned short* B = A + (size_t)BATCH * KTOT;          // 8*16 tiles  = 1 MiB

    prep_kernel<<<512 + 128, 256, 0, stream>>>(x, c, w_b, w_s, grid, A, B);
    gemm_kernel<<<256, 512, 0, stream>>>(A, B, outp);
}

// Round 10
// 18.395 us; speedup vs baseline: 3.4692x; 1.1448x over previous
//
#include <hip/hip_runtime.h>

// Problem constants
#define BATCH 2048
#define IN    512
#define OUT   512
#define NG    8
#define KTOT  1024   // concatenated K: [S | silu] x [Cw | w_b]

// GEMM tiling: 64x64 tile, BK=64, linear row-major ws [row][KTOT].
// LDS bank-conflict fix via BOTH-sides swizzle with LINEAR LDS (rule #21 +
// s09): global SOURCE chunk of each gload_lds lane is XOR-permuted
// (gsc = cc ^ (row&7)); ds_read applies the same XOR. LDS itself is linear.
#define TILE_SHORTS 4096       // 64*64
#define NIT 16

typedef __attribute__((ext_vector_type(8))) short bf16x8;
typedef __attribute__((ext_vector_type(4))) float f32x4;

__device__ inline unsigned short f2bf(float f) {
    union { float f; unsigned int u; } v; v.f = f;
    unsigned int r = v.u + 0x7fffu + ((v.u >> 16) & 1u);
    return (unsigned short)(r >> 16);
}

__device__ inline void gload_lds16(const void* g, void* l) {
    __builtin_amdgcn_global_load_lds((const __attribute__((address_space(1))) void*)g,
                                     (__attribute__((address_space(3))) void*)l, 16, 0, 0);
}

// ---------------------------------------------------------------------------
// Fused prep (round-4 verbatim, linear ws): blocks [0,512) build A',
// blocks [512,640) build B'.
//   A'[b][i] = sum_n exp(-(x[b,i]-g_n)^2)   A'[b][512+i] = silu(x[b,i])
//   B'[o][i] = (sum_a c[a,o,i]) * w_s[o,i]  B'[o][512+i] = w_b[o,i]
// Spline via uniform-grid factorization: 3 exp + Horner instead of 9 exp.
// ---------------------------------------------------------------------------
__global__ __launch_bounds__(256) void prep_kernel(const float* __restrict__ x,
                                                   const float* __restrict__ c,
                                                   const float* __restrict__ w_b,
                                                   const float* __restrict__ w_s,
                                                   const float* __restrict__ grid,
                                                   unsigned short* __restrict__ A,
                                                   unsigned short* __restrict__ B) {
    int blk = blockIdx.x;
    int tid = threadIdx.x;
    if (blk < 512) {
        int e = (blk * 256 + tid) * 8;       // element base in x (row-aligned)
        float g0 = grid[0];
        float dl = grid[1] - g0;             // uniform spacing (4/7)
        float d2 = dl * dl;
        float dn[NG];
#pragma unroll
        for (int n = 0; n < NG; ++n) dn[n] = __expf(-d2 * (float)(n * n));
        float4 x0 = *(const float4*)&x[e];
        float4 x1 = *(const float4*)&x[e + 4];
        float xv[8] = {x0.x, x0.y, x0.z, x0.w, x1.x, x1.y, x1.z, x1.w};
        unsigned short sv[8], lv[8];
#pragma unroll
        for (int j = 0; j < 8; ++j) {
            float u  = xv[j] - g0;
            float e1 = __expf(-u * u);
            float q  = __expf(2.f * dl * u);
            float p  = dn[NG - 1];
#pragma unroll
            for (int n = NG - 2; n >= 0; --n) p = p * q + dn[n];
            sv[j] = f2bf(e1 * p);
            lv[j] = f2bf(xv[j] / (1.f + __expf(-xv[j])));
        }
        int b = e >> 9, i = e & 511;
        *(int4*)&A[b * KTOT + i]       = *(int4*)sv;
        *(int4*)&A[b * KTOT + 512 + i] = *(int4*)lv;
    } else {
        int e = ((blk - 512) * 256 + tid) * 8;
        float acc[8] = {};
#pragma unroll
        for (int a = 0; a < NG; ++a) {
            float4 c0 = *(const float4*)&c[(size_t)a * (OUT * IN) + e];
            float4 c1 = *(const float4*)&c[(size_t)a * (OUT * IN) + e + 4];
            acc[0] += c0.x; acc[1] += c0.y; acc[2] += c0.z; acc[3] += c0.w;
            acc[4] += c1.x; acc[5] += c1.y; acc[6] += c1.z; acc[7] += c1.w;
        }
        float4 s0 = *(const float4*)&w_s[e];
        float4 s1 = *(const float4*)&w_s[e + 4];
        float sw[8] = {s0.x, s0.y, s0.z, s0.w, s1.x, s1.y, s1.z, s1.w};
        float4 b0 = *(const float4*)&w_b[e];
        float4 b1 = *(const float4*)&w_b[e + 4];
        float bw[8] = {b0.x, b0.y, b0.z, b0.w, b1.x, b1.y, b1.z, b1.w};
        unsigned short cv[8], bv[8];
#pragma unroll
        for (int j = 0; j < 8; ++j) { cv[j] = f2bf(acc[j] * sw[j]); bv[j] = f2bf(bw[j]); }
        int o = e >> 9, i = e & 511;
        *(int4*)&B[o * KTOT + i]       = *(int4*)cv;
        *(int4*)&B[o * KTOT + 512 + i] = *(int4*)bv;
    }
}

// ---------------------------------------------------------------------------
// bf16 MFMA GEMM: out[2048][512] = A'[2048][1024] * B'[512][1024]^T
// 256 blocks (1/CU, XCD decode), 512 threads = 8 waves:
// (wm,wn) = 32x32 output quadrant, ks = K-slice of 32 within BK=64.
// T3+T4: 3-buffer LDS, gload_lds staging 2 tiles ahead, counted
// s_waitcnt vmcnt(2) + raw s_barrier -> next-tile loads stay in flight
// across the barrier (no full drain).
// ---------------------------------------------------------------------------
__global__ __launch_bounds__(512) void gemm_kernel(const unsigned short* __restrict__ A,
                                                   const unsigned short* __restrict__ B,
                                                   float* __restrict__ outp) {
    __shared__ short As[3][TILE_SHORTS];
    __shared__ short Bs[3][TILE_SHORTS];

    int tid  = threadIdx.x;
    int lane = tid & 63;
    int w    = tid >> 6;               // 0..7
    int wm   = (w >> 2) & 1;
    int wn   = (w >> 1) & 1;
    int ks   = w & 1;                  // K-slice within BK
    int lr   = lane & 15, lg = lane >> 4;

    int bid  = blockIdx.x;
    int mg   = bid & 7;                // XCD id
    int rest = bid >> 3;
    int sub  = rest >> 3;              // 0..3
    int ncol = rest & 7;               // 0..7
    int mt   = mg * 4 + sub;           // 0..31
    int m0   = mt * 64;
    int n0   = ncol * 64;

    // staging: thread -> LDS (row=tid>>3, chunk=tid&7) linear dest tid*16B;
    // global source chunk XOR-permuted so LDS holds the swizzled layout.
    int srow = tid >> 3;
    int gsc  = (tid & 7) ^ (srow & 7);
    const unsigned short* a_src = A + (size_t)(m0 + srow) * KTOT + gsc * 8;
    const unsigned short* b_src = B + (size_t)(n0 + srow) * KTOT + gsc * 8;

    // swizzled ds_read chunk: rows are congruent to lr mod 8 for all frags
    int swc  = ((ks * 4 + lg) ^ (lr & 7)) * 8;
    int ra0  = (wm * 32 + lr)      * 64 + swc;
    int ra1  = (wm * 32 + 16 + lr) * 64 + swc;
    int rb0  = (wn * 32 + lr)      * 64 + swc;
    int rb1  = (wn * 32 + 16 + lr) * 64 + swc;

    f32x4 acc00 = {0.f, 0.f, 0.f, 0.f};
    f32x4 acc01 = {0.f, 0.f, 0.f, 0.f};
    f32x4 acc10 = {0.f, 0.f, 0.f, 0.f};
    f32x4 acc11 = {0.f, 0.f, 0.f, 0.f};

    // STAGE(t, buf): stage K-tile t into LDS buffer buf (2 gload_lds16 each)
#define STAGE(t, buf) do { \
        gload_lds16(a_src + (t) * 64, &As[buf][tid * 8]); \
        gload_lds16(b_src + (t) * 64, &Bs[buf][tid * 8]); \
    } while (0)

    // prologue: stage t0->buf0, t1->buf1; wait t0 (t1's 2 loads in flight)
    STAGE(0, 0);
    STAGE(1, 1);
    asm volatile("s_waitcnt vmcnt(2)" ::: "memory");
    __builtin_amdgcn_s_barrier();
    __builtin_amdgcn_sched_barrier(0);

#pragma unroll
    for (int it = 0; it < NIT; ++it) {
        int cur = it % 3;
        if (it + 2 < NIT) STAGE(it + 2, (it + 2) % 3);   // tile, buffer (FIXED)
        bf16x8 a0 = *(const bf16x8*)&As[cur][ra0];
        bf16x8 a1 = *(const bf16x8*)&As[cur][ra1];
        bf16x8 b0 = *(const bf16x8*)&Bs[cur][rb0];
        bf16x8 b1 = *(const bf16x8*)&Bs[cur][rb1];
        acc00 = __builtin_amdgcn_mfma_f32_16x16x32_bf16(a0, b0, acc00, 0, 0, 0);
        acc01 = __builtin_amdgcn_mfma_f32_16x16x32_bf16(a0, b1, acc01, 0, 0, 0);
        acc10 = __builtin_amdgcn_mfma_f32_16x16x32_bf16(a1, b0, acc10, 0, 0, 0);
        acc11 = __builtin_amdgcn_mfma_f32_16x16x32_bf16(a1, b1, acc11, 0, 0, 0);
        if (it + 1 < NIT) {
            // drain tile it+1's loads only; it+2's (if any) stay in flight
            if (it + 2 < NIT) asm volatile("s_waitcnt vmcnt(2)" ::: "memory");
            else              asm volatile("s_waitcnt vmcnt(0)" ::: "memory");
            __builtin_amdgcn_s_barrier();
            __builtin_amdgcn_sched_barrier(0);
        }
    }
#undef STAGE

    // epilogue: all waves' last ds_reads done (consumed by MFMA) -> barrier,
    // then reuse As[0..1] as the cross-ks reduction scratch (16KB).
    __syncthreads();
    float* Ls = (float*)&As[0][0];
    int p = w >> 1;                    // quadrant id 0..3
    if (ks == 1) {
        *(f32x4*)&Ls[p * 1024 + lane * 16 + 0]  = acc00;
        *(f32x4*)&Ls[p * 1024 + lane * 16 + 4]  = acc01;
        *(f32x4*)&Ls[p * 1024 + lane * 16 + 8]  = acc10;
        *(f32x4*)&Ls[p * 1024 + lane * 16 + 12] = acc11;
    }
    __syncthreads();
    if (ks == 0) {
        f32x4 p00 = *(const f32x4*)&Ls[p * 1024 + lane * 16 + 0];
        f32x4 p01 = *(const f32x4*)&Ls[p * 1024 + lane * 16 + 4];
        f32x4 p10 = *(const f32x4*)&Ls[p * 1024 + lane * 16 + 8];
        f32x4 p11 = *(const f32x4*)&Ls[p * 1024 + lane * 16 + 12];
        // C/D layout: col = lane&15, row = (lane>>4)*4 + reg   [measured m89/m91]
        int orow = m0 + wm * 32 + lg * 4;
        int ocol = n0 + wn * 32 + lr;
#pragma unroll
        for (int r = 0; r < 4; ++r) {
            outp[(size_t)(orow + r) * OUT + ocol]           = acc00[r] + p00[r];
            outp[(size_t)(orow + r) * OUT + ocol + 16]      = acc01[r] + p01[r];
            outp[(size_t)(orow + 16 + r) * OUT + ocol]      = acc10[r] + p10[r];
            outp[(size_t)(orow + 16 + r) * OUT + ocol + 16] = acc11[r] + p11[r];
        }
    }
}

extern "C" void kernel_launch(void* const* d_in, const int* in_sizes, int n_in,
                              void* d_out, int out_size, void* d_ws, size_t ws_size,
                              hipStream_t stream) {
    (void)in_sizes; (void)n_in; (void)out_size; (void)ws_size;
    const float* x    = (const float*)d_in[0];
    const float* c    = (const float*)d_in[1];
    const float* w_b  = (const float*)d_in[2];
    const float* w_s  = (const float*)d_in[3];
    const float* grid = (const float*)d_in[4];
    float* outp = (float*)d_out;

    unsigned short* A = (unsigned short*)d_ws;             // 2048x1024 bf16 = 4 MiB
    unsigned short* B = A + (size_t)BATCH * KTOT;          // 512x1024 bf16 = 1 MiB

    prep_kernel<<<512 + 128, 256, 0, stream>>>(x, c, w_b, w_s, grid, A, B);
    gemm_kernel<<<256, 512, 0, stream>>>(A, B, outp);
}